// Round 17
// baseline (97.353 us; speedup 1.0000x reference)
//
#include <hip/hip_runtime.h>

#define BLOCK 256
#define LOG_2PI_F 1.8378770664093453f

typedef float v4f __attribute__((ext_vector_type(4)));

// ws layout (float offsets):
//   0..7   : stats: [2] ld_sum0 [3] ld_sum1 [4] cnt0 [5] cnt1
//   16     : p_tab [2*D]   (= 0.5*exp(-2*lsd))
//   16+2D  : q_tab [2*D]   (= 2*p*mu)
//   PART0  : partials [2(z)][G][2][Dp]   (plane 0 = sumAll, 1 = sumC1), Dp = D
//
// out layout: [0] prior | [1,1+2D) mus | [1+2D,1+4D) lsds |
//             [1+4D,1+4D+N) logp | [1+4D+N, +2) log_p_total

__device__ __forceinline__ float4 ldnt4(const float4* p) {
    v4f t = __builtin_nontemporal_load((const v4f*)p);
    float4 r; r.x = t.x; r.y = t.y; r.z = t.z; r.w = t.w;
    return r;
}

// shared stats helper: counts + per-class logdet sums (run by one block)
__device__ void do_stats(const int* __restrict__ target,
                         const float* __restrict__ logdet,
                         float* __restrict__ stats, int N)
{
    const int tid = threadIdx.x;
    float ldA = 0.f, ld1 = 0.f;
    int   c1  = 0;
    if ((N & 3) == 0) {
        const int4*   t4 = reinterpret_cast<const int4*>(target);
        const float4* l4 = reinterpret_cast<const float4*>(logdet);
        for (int i = tid; i < (N >> 2); i += BLOCK) {
            const int4   t = t4[i];
            const float4 v = l4[i];
            ldA += v.x + v.y + v.z + v.w;
            if (t.x) { c1++; ld1 += v.x; }
            if (t.y) { c1++; ld1 += v.y; }
            if (t.z) { c1++; ld1 += v.z; }
            if (t.w) { c1++; ld1 += v.w; }
        }
    } else {
        for (int n = tid; n < N; n += BLOCK) {
            const float v = logdet[n];
            ldA += v;
            if (target[n]) { c1++; ld1 += v; }
        }
    }
    __shared__ float sB[BLOCK], sC[BLOCK];
    __shared__ int   sI[BLOCK];
    sB[tid] = ldA; sC[tid] = ld1; sI[tid] = c1;
    __syncthreads();
    for (int off = BLOCK / 2; off > 0; off >>= 1) {
        if (tid < off) {
            sB[tid] += sB[tid + off];
            sC[tid] += sC[tid + off];
            sI[tid] += sI[tid + off];
        }
        __syncthreads();
    }
    if (tid == 0) {
        stats[2] = sB[0] - sC[0];          // ld_sum0
        stats[3] = sC[0];                  // ld_sum1
        stats[4] = (float)(N - sI[0]);     // cnt0
        stats[5] = (float)sI[0];           // cnt1
    }
}

// fast path (D == 3072): PER-WAVE SEQUENTIAL ROW SWEEP — each wave owns
// whole rows and reads each row front-to-back as one 12 KB contiguous run
// (12 x float4 at consecutive 1KB offsets), byte-identical to k_logp's
// access pattern. Lane accumulates 12 column-position partials per plane;
// the block's 4 waves LDS-combine into one full-width partial slot.
__global__ __launch_bounds__(BLOCK) void k_colsum3(
    const float* __restrict__ src,      // mean (zidx=0) or log_sd (zidx=1)
    const int*   __restrict__ target,
    const float* __restrict__ logdet,
    float* __restrict__ partials,
    float* __restrict__ stats,
    int N, int G, int zidx)
{
    const int tid  = threadIdx.x;
    const int wave = tid >> 6;
    const int lane = tid & 63;
    const int b    = blockIdx.x;            // block slot, 0..G-1
    const int W    = b * 4 + wave;          // global wave id
    const int TotW = G * 4;

    const float4* s4 = reinterpret_cast<const float4*>(src);

    float4 rA[12];
    float4 rC[12];
    #pragma unroll
    for (int j = 0; j < 12; ++j) {
        rA[j] = make_float4(0.f, 0.f, 0.f, 0.f);
        rC[j] = make_float4(0.f, 0.f, 0.f, 0.f);
    }

    for (int r = W; r < N; r += TotW) {
        const float w = target[r] ? 1.f : 0.f;   // wave-uniform
        const float4* row = s4 + (size_t)r * 768 + lane;
        #pragma unroll
        for (int j = 0; j < 12; ++j) {           // 12 consecutive 1KB chunks
            const float4 d = row[j * 64];
            rA[j].x += d.x; rA[j].y += d.y; rA[j].z += d.z; rA[j].w += d.w;
            rC[j].x = fmaf(d.x, w, rC[j].x);
            rC[j].y = fmaf(d.y, w, rC[j].y);
            rC[j].z = fmaf(d.z, w, rC[j].z);
            rC[j].w = fmaf(d.w, w, rC[j].w);
        }
    }

    // combine the 4 waves' full-width partials in LDS (4 barrier phases)
    __shared__ float4 accA[768];   // 12 KB
    __shared__ float4 accC[768];   // 12 KB
    for (int ph = 0; ph < 4; ++ph) {
        if (wave == ph) {
            #pragma unroll
            for (int j = 0; j < 12; ++j) {
                const int idx = j * 64 + lane;
                if (ph == 0) {
                    accA[idx] = rA[j];
                    accC[idx] = rC[j];
                } else {
                    float4 a = accA[idx];
                    a.x += rA[j].x; a.y += rA[j].y;
                    a.z += rA[j].z; a.w += rA[j].w;
                    accA[idx] = a;
                    float4 c = accC[idx];
                    c.x += rC[j].x; c.y += rC[j].y;
                    c.z += rC[j].z; c.w += rC[j].w;
                    accC[idx] = c;
                }
            }
        }
        __syncthreads();
    }

    // coalesced store of the block's combined slot
    float* sbase = partials + ((size_t)zidx * G + b) * (2 * 3072);
    float4* pl0 = reinterpret_cast<float4*>(sbase);          // plane sumAll
    float4* pl1 = reinterpret_cast<float4*>(sbase + 3072);   // plane sumC1
    pl0[tid]       = accA[tid];
    pl0[tid + 256] = accA[tid + 256];
    pl0[tid + 512] = accA[tid + 512];
    pl1[tid]       = accC[tid];
    pl1[tid + 256] = accC[tid + 256];
    pl1[tid + 512] = accC[tid + 512];

    if (b == 0 && zidx == 0) do_stats(target, logdet, stats, N);
}

// generic fallback (any D): round-robin rows, column-group blocks
__global__ __launch_bounds__(BLOCK, 4) void k_colsum_gen(
    const float* __restrict__ mean,
    const float* __restrict__ log_sd,
    const int*   __restrict__ target,
    const float* __restrict__ logdet,
    float* __restrict__ partials,
    float* __restrict__ stats,
    int N, int D4, int Dp, int G)
{
    const int c4 = blockIdx.x * BLOCK + threadIdx.x;
    const bool colOK = (c4 < D4);
    const int by = blockIdx.y;

    const float4* src4 =
        reinterpret_cast<const float4*>(blockIdx.z == 0 ? mean : log_sd);
    const float4* p = src4 + (size_t)by * D4 + (colOK ? c4 : 0);
    const size_t rstep = (size_t)G * D4;
    const int nk = (by < N) ? ((N - 1 - by) / G + 1) : 0;

    float4 sA = make_float4(0.f,0.f,0.f,0.f);
    float4 s1 = make_float4(0.f,0.f,0.f,0.f);
    for (int k = 0; k < nk; ++k) {
        const float w = target[by + k * G] ? 1.f : 0.f;
        const float4 d = p[(size_t)k * rstep];
        sA.x += d.x; sA.y += d.y; sA.z += d.z; sA.w += d.w;
        s1.x = fmaf(d.x, w, s1.x);
        s1.y = fmaf(d.y, w, s1.y);
        s1.z = fmaf(d.z, w, s1.z);
        s1.w = fmaf(d.w, w, s1.w);
    }

    if (colOK) {
        float* base = partials +
            ((size_t)blockIdx.z * G + by) * (2 * (size_t)Dp);
        reinterpret_cast<float4*>(base)[c4]      = sA;
        reinterpret_cast<float4*>(base + Dp)[c4] = s1;
    }
    if (blockIdx.x == 0 && by == 0 && blockIdx.z == 0)
        do_stats(target, logdet, stats, N);
}

// reduce partials over G slots; NT loads (partials dead after this)
__global__ __launch_bounds__(BLOCK) void k_reduce_finalize(
    const float* __restrict__ partials,
    float* __restrict__ ws,
    float* __restrict__ out,
    int D, int Dp, int G)
{
    const int sub  = threadIdx.x & 7;
    const int slot = threadIdx.x >> 3;                 // 0..31
    const int oidx = blockIdx.x * 32 + slot;           // [0, 2*D)
    const bool ok  = (oidx < 2 * D);
    const int cls = ok ? (oidx / D) : 0;
    const int col = ok ? (oidx - cls * D) : 0;

    const size_t strideBY = 2 * (size_t)Dp;
    const size_t zoff     = (size_t)G * strideBY;
    const int per = G >> 3;

    float mA = 0.f, m1 = 0.f, lA = 0.f, l1 = 0.f;
    for (int j = 0; j < per; ++j) {
        const size_t base = (size_t)(sub * per + j) * strideBY + col;
        mA += __builtin_nontemporal_load(&partials[base]);
        m1 += __builtin_nontemporal_load(&partials[base + Dp]);
        lA += __builtin_nontemporal_load(&partials[zoff + base]);
        l1 += __builtin_nontemporal_load(&partials[zoff + base + Dp]);
    }
    #pragma unroll
    for (int s = 1; s <= 4; s <<= 1) {
        mA += __shfl_xor(mA, s);
        m1 += __shfl_xor(m1, s);
        lA += __shfl_xor(lA, s);
        l1 += __shfl_xor(l1, s);
    }

    if (ok && sub == 0) {
        const float cnt = ws[4 + cls];
        const float m = (cls ? m1 : (mA - m1)) / cnt;
        const float l = (cls ? l1 : (lA - l1)) / cnt;
        out[1 + oidx]         = m;   // mus
        out[1 + 2 * D + oidx] = l;   // lsds
        float* p_tab = ws + 16;
        float* q_tab = p_tab + 2 * D;
        const float pv = 0.5f * expf(-2.f * l);
        p_tab[oidx] = pv;
        q_tab[oidx] = 2.f * pv * m;
    }
}

// per-row logp body; NT selects streaming (evict-first) z loads
template<bool NT>
__device__ __forceinline__ float row_logp(const float4* __restrict__ z4,
                                          const float4* __restrict__ p4,
                                          const float4* __restrict__ q4,
                                          int D4, int lane)
{
    float acc = 0.f;
    int i = lane;
    for (; i + 64 < D4; i += 128) {
        float4 zz0, zz1;
        if constexpr (NT) { zz0 = ldnt4(z4 + i); zz1 = ldnt4(z4 + i + 64); }
        else              { zz0 = z4[i];         zz1 = z4[i + 64]; }
        const float4 pp0 = p4[i];      const float4 pp1 = p4[i + 64];
        const float4 qq0 = q4[i];      const float4 qq1 = q4[i + 64];
        acc += zz0.x * (qq0.x - pp0.x * zz0.x);
        acc += zz0.y * (qq0.y - pp0.y * zz0.y);
        acc += zz0.z * (qq0.z - pp0.z * zz0.z);
        acc += zz0.w * (qq0.w - pp0.w * zz0.w);
        acc += zz1.x * (qq1.x - pp1.x * zz1.x);
        acc += zz1.y * (qq1.y - pp1.y * zz1.y);
        acc += zz1.z * (qq1.z - pp1.z * zz1.z);
        acc += zz1.w * (qq1.w - pp1.w * zz1.w);
    }
    for (; i < D4; i += 64) {
        float4 zz;
        if constexpr (NT) zz = ldnt4(z4 + i);
        else              zz = z4[i];
        const float4 pp = p4[i];
        const float4 qq = q4[i];
        acc += zz.x * (qq.x - pp.x * zz.x);
        acc += zz.y * (qq.y - pp.y * zz.y);
        acc += zz.z * (qq.z - pp.z * zz.z);
        acc += zz.w * (qq.w - pp.w * zz.w);
    }
    return acc;
}

__global__ __launch_bounds__(BLOCK) void k_logp(
    const float* __restrict__ z,
    const int*   __restrict__ target,
    const float* __restrict__ ws,
    float* __restrict__ logp_out,
    int N, int D)
{
    const int wave = threadIdx.x >> 6;
    const int lane = threadIdx.x & 63;
    const int n    = blockIdx.x * 4 + wave;
    const int D4   = D >> 2;
    if (n >= N) return;

    const int t = __builtin_amdgcn_readfirstlane(target[n]);
    const float4* z4 = reinterpret_cast<const float4*>(z) + (size_t)n * D4;
    const float4* p4 = reinterpret_cast<const float4*>(ws + 16) + (size_t)t * D4;
    const float4* q4 = p4 + 2 * D4;

    // first half of z non-temporal (R13 best-known configuration)
    float acc;
    if (n < (N >> 1)) acc = row_logp<true >(z4, p4, q4, D4, lane);
    else              acc = row_logp<false>(z4, p4, q4, D4, lane);

    #pragma unroll
    for (int m = 32; m >= 1; m >>= 1) acc += __shfl_xor(acc, m);
    if (lane == 0) logp_out[n] = acc;        // Bc added in k_finalize2
}

// epilogue: per-class Bc from mus/lsds, patch logp, class means, prior
__global__ __launch_bounds__(1024) void k_finalize2(
    const int*   __restrict__ target,
    const float* __restrict__ stats,
    float* __restrict__ out,
    int N, int D, int out_off)
{
    const int tid = threadIdx.x;
    const float* mus  = out + 1;
    const float* lsds = out + 1 + 2 * D;
    float* logp = out + 1 + 4 * D;

    // phase 1: Bc[cls] = sum_d ( -0.5*log2pi - l - 0.5*exp(-2l)*m^2 )
    float b0 = 0.f, b1 = 0.f;
    for (int idx = tid; idx < 2 * D; idx += 1024) {
        const float m = mus[idx];
        const float l = lsds[idx];
        const float b = -0.5f * LOG_2PI_F - l - 0.5f * expf(-2.f * l) * m * m;
        if (idx < D) b0 += b; else b1 += b;
    }
    __shared__ float s0[1024];
    __shared__ float s1[1024];
    s0[tid] = b0; s1[tid] = b1;
    __syncthreads();
    for (int off = 512; off > 0; off >>= 1) {
        if (tid < off) {
            s0[tid] += s0[tid + off];
            s1[tid] += s1[tid + off];
        }
        __syncthreads();
    }
    const float B0 = s0[0];
    const float B1 = s1[0];
    __syncthreads();

    // phase 2: patch logp with Bc, accumulate per-class sums
    float cA = 0.f, c1 = 0.f;
    for (int i = tid; i < N; i += 1024) {
        const int   t = target[i];
        const float v = logp[i] + (t ? B1 : B0);
        logp[i] = v;
        cA += v;
        if (t) c1 += v;
    }
    s0[tid] = cA; s1[tid] = c1;
    __syncthreads();
    for (int off = 512; off > 0; off >>= 1) {
        if (tid < off) {
            s0[tid] += s0[tid + off];
            s1[tid] += s1[tid + off];
        }
        __syncthreads();
    }
    if (tid == 0) {
        const float lp0 = (s0[0] - s1[0]) / stats[4];
        const float lp1 = s1[0] / stats[5];
        const float ld0 = stats[2] / stats[4];
        const float ld1 = stats[3] / stats[5];
        out[out_off]     = lp0;            // log_p_total[0]
        out[out_off + 1] = lp1;            // log_p_total[1]
        out[0] = 0.5f * ((lp0 + ld0) + (lp1 + ld1));  // prior_logprob
    }
}

extern "C" void kernel_launch(void* const* d_in, const int* in_sizes, int n_in,
                              void* d_out, int out_size, void* d_ws, size_t ws_size,
                              hipStream_t stream)
{
    const float* z      = (const float*)d_in[0];
    const float* mean   = (const float*)d_in[1];
    const float* log_sd = (const float*)d_in[2];
    const float* logdet = (const float*)d_in[3];
    const int*   target = (const int*)d_in[4];
    float* out = (float*)d_out;
    float* ws  = (float*)d_ws;

    const int N  = in_sizes[3];            // 8192
    const int D  = in_sizes[0] / N;        // 3072
    const int D4 = D >> 2;                 // 768
    const int Dp = D;                      // plane width

    size_t part0 = (size_t)(16 + 4 * D);
    part0 = (part0 + 255) & ~(size_t)255;

    // pick G (power of 2, >= 8): 512 -> 25MB partials
    int G = 512;
    while (G > 8 &&
           (part0 + (size_t)2 * G * 2 * Dp) * sizeof(float) > ws_size)
        G >>= 1;

    float* partials = ws + part0;

    // pass 1: per-wave-sequential column partial sums, one array per launch
    if (D == 3072) {
        k_colsum3<<<G, BLOCK, 0, stream>>>(mean,   target, logdet,
                                           partials, ws, N, G, 0);
        k_colsum3<<<G, BLOCK, 0, stream>>>(log_sd, target, logdet,
                                           partials, ws, N, G, 1);
    } else {
        dim3 g1((D4 + BLOCK - 1) / BLOCK, G, 2);
        k_colsum_gen<<<g1, BLOCK, 0, stream>>>(mean, log_sd, target, logdet,
                                               partials, ws, N, D4, Dp, G);
    }

    // reduce partials (NT) + finalize class params + build p/q tables
    const int nred = (2 * D + 31) / 32;
    k_reduce_finalize<<<nred, BLOCK, 0, stream>>>(partials, ws, out, D, Dp, G);

    // pass 2: per-sample logp (half of z non-temporal — R13 config)
    float* logp_out = out + 1 + 4 * D;
    k_logp<<<(N + 3) / 4, BLOCK, 0, stream>>>(z, target, ws, logp_out, N, D);

    // epilogue: Bc + patch logp + class means + prior
    k_finalize2<<<1, 1024, 0, stream>>>(target, ws, out, N, D, 1 + 4 * D + N);
}

// Round 18
// 93.633 us; speedup vs baseline: 1.0397x; 1.0397x over previous
//
#include <hip/hip_runtime.h>

#define BLOCK 256
#define LOG_2PI_F 1.8378770664093453f

typedef float v4f __attribute__((ext_vector_type(4)));

// ws layout (float offsets):
//   0..7   : stats: [2] ld_sum0 [3] ld_sum1 [4] cnt0 [5] cnt1
//   16     : p_tab [2*D]   (= 0.5*exp(-2*lsd))
//   16+2D  : q_tab [2*D]   (= 2*p*mu)
//   PART0  : partials [2(z)][G][2][Dp]  (plane 0 = sumAll, 1 = sumC1), Dp = D
//
// out layout: [0] prior | [1,1+2D) mus | [1+2D,1+4D) lsds |
//             [1+4D,1+4D+N) logp | [1+4D+N, +2) log_p_total

__device__ __forceinline__ float4 ldnt4(const float4* p) {
    v4f t = __builtin_nontemporal_load((const v4f*)p);
    float4 r; r.x = t.x; r.y = t.y; r.z = t.z; r.w = t.w;
    return r;
}

// shared stats helper: counts + per-class logdet sums (run by one block)
__device__ void do_stats(const int* __restrict__ target,
                         const float* __restrict__ logdet,
                         float* __restrict__ stats, int N)
{
    const int tid = threadIdx.x;
    float ldA = 0.f, ld1 = 0.f;
    int   c1  = 0;
    if ((N & 3) == 0) {
        const int4*   t4 = reinterpret_cast<const int4*>(target);
        const float4* l4 = reinterpret_cast<const float4*>(logdet);
        for (int i = tid; i < (N >> 2); i += BLOCK) {
            const int4   t = t4[i];
            const float4 v = l4[i];
            ldA += v.x + v.y + v.z + v.w;
            if (t.x) { c1++; ld1 += v.x; }
            if (t.y) { c1++; ld1 += v.y; }
            if (t.z) { c1++; ld1 += v.z; }
            if (t.w) { c1++; ld1 += v.w; }
        }
    } else {
        for (int n = tid; n < N; n += BLOCK) {
            const float v = logdet[n];
            ldA += v;
            if (target[n]) { c1++; ld1 += v; }
        }
    }
    __shared__ float sB[BLOCK], sC[BLOCK];
    __shared__ int   sI[BLOCK];
    sB[tid] = ldA; sC[tid] = ld1; sI[tid] = c1;
    __syncthreads();
    for (int off = BLOCK / 2; off > 0; off >>= 1) {
        if (tid < off) {
            sB[tid] += sB[tid + off];
            sC[tid] += sC[tid + off];
            sI[tid] += sI[tid + off];
        }
        __syncthreads();
    }
    if (tid == 0) {
        stats[2] = sB[0] - sC[0];          // ld_sum0
        stats[3] = sC[0];                  // ld_sum1
        stats[4] = (float)(N - sI[0]);     // cnt0
        stats[5] = (float)sI[0];           // cnt1
    }
}

// fast path (D == 3072, N % 512 == 0): FLAT THREAD-LINEAR grid-stride —
// byte-identical address stream to the m13 6.3 TB/s float4 copy.
// T = 1536 blocks x 256 = 393216 float4 = exactly 512 rows per iteration.
// Thread t: column t%768 (iteration-invariant), row-group t/768
// (block-uniform), row at iter k = rg + 512k. One float4 load + one
// block-uniform weight + 8 FMA per iteration; 2 float4 accumulators.
__global__ __launch_bounds__(BLOCK) void k_colsum3_flat(
    const float* __restrict__ src,      // mean (zidx=0) or log_sd (zidx=1)
    const int*   __restrict__ target,
    const float* __restrict__ logdet,
    float* __restrict__ partials,
    float* __restrict__ stats,
    int N, int zidx)
{
    const int t    = blockIdx.x * BLOCK + threadIdx.x;   // global thread
    const int T    = gridDim.x * BLOCK;                  // 393216
    const int rg   = __builtin_amdgcn_readfirstlane(t / 768);  // block-uniform
    const int col4 = t - rg * 768;
    const int rowsPerIter = T / 768;                     // 512
    const int iters = N / rowsPerIter;                   // 16

    const float4* p = reinterpret_cast<const float4*>(src) + t;

    float4 sA = make_float4(0.f, 0.f, 0.f, 0.f);
    float4 sC = make_float4(0.f, 0.f, 0.f, 0.f);

    #pragma unroll 4
    for (int k = 0; k < iters; ++k) {
        const float w = target[rg + k * rowsPerIter] ? 1.f : 0.f;
        const float4 d = p[(size_t)k * T];
        sA.x += d.x; sA.y += d.y; sA.z += d.z; sA.w += d.w;
        sC.x = fmaf(d.x, w, sC.x);
        sC.y = fmaf(d.y, w, sC.y);
        sC.z = fmaf(d.z, w, sC.z);
        sC.w = fmaf(d.w, w, sC.w);
    }

    // coalesced partial store: slot = row-group, same layout as reduce expects
    float* sbase = partials + ((size_t)zidx * rowsPerIter + rg) * (2 * 3072);
    reinterpret_cast<float4*>(sbase)[col4]        = sA;   // plane sumAll
    reinterpret_cast<float4*>(sbase + 3072)[col4] = sC;   // plane sumC1

    if (blockIdx.x == 0 && zidx == 0) do_stats(target, logdet, stats, N);
}

// generic fallback (any D): round-robin rows, column-group blocks
__global__ __launch_bounds__(BLOCK, 4) void k_colsum_gen(
    const float* __restrict__ mean,
    const float* __restrict__ log_sd,
    const int*   __restrict__ target,
    const float* __restrict__ logdet,
    float* __restrict__ partials,
    float* __restrict__ stats,
    int N, int D4, int Dp, int G)
{
    const int c4 = blockIdx.x * BLOCK + threadIdx.x;
    const bool colOK = (c4 < D4);
    const int by = blockIdx.y;

    const float4* src4 =
        reinterpret_cast<const float4*>(blockIdx.z == 0 ? mean : log_sd);
    const float4* p = src4 + (size_t)by * D4 + (colOK ? c4 : 0);
    const size_t rstep = (size_t)G * D4;
    const int nk = (by < N) ? ((N - 1 - by) / G + 1) : 0;

    float4 sA = make_float4(0.f,0.f,0.f,0.f);
    float4 s1 = make_float4(0.f,0.f,0.f,0.f);
    for (int k = 0; k < nk; ++k) {
        const float w = target[by + k * G] ? 1.f : 0.f;
        const float4 d = p[(size_t)k * rstep];
        sA.x += d.x; sA.y += d.y; sA.z += d.z; sA.w += d.w;
        s1.x = fmaf(d.x, w, s1.x);
        s1.y = fmaf(d.y, w, s1.y);
        s1.z = fmaf(d.z, w, s1.z);
        s1.w = fmaf(d.w, w, s1.w);
    }

    if (colOK) {
        float* base = partials +
            ((size_t)blockIdx.z * G + by) * (2 * (size_t)Dp);
        reinterpret_cast<float4*>(base)[c4]      = sA;
        reinterpret_cast<float4*>(base + Dp)[c4] = s1;
    }
    if (blockIdx.x == 0 && by == 0 && blockIdx.z == 0)
        do_stats(target, logdet, stats, N);
}

// reduce partials over G slots; NT loads (partials dead after this)
__global__ __launch_bounds__(BLOCK) void k_reduce_finalize(
    const float* __restrict__ partials,
    float* __restrict__ ws,
    float* __restrict__ out,
    int D, int Dp, int G)
{
    const int sub  = threadIdx.x & 7;
    const int slot = threadIdx.x >> 3;                 // 0..31
    const int oidx = blockIdx.x * 32 + slot;           // [0, 2*D)
    const bool ok  = (oidx < 2 * D);
    const int cls = ok ? (oidx / D) : 0;
    const int col = ok ? (oidx - cls * D) : 0;

    const size_t strideBY = 2 * (size_t)Dp;
    const size_t zoff     = (size_t)G * strideBY;
    const int per = G >> 3;

    float mA = 0.f, m1 = 0.f, lA = 0.f, l1 = 0.f;
    for (int j = 0; j < per; ++j) {
        const size_t base = (size_t)(sub * per + j) * strideBY + col;
        mA += __builtin_nontemporal_load(&partials[base]);
        m1 += __builtin_nontemporal_load(&partials[base + Dp]);
        lA += __builtin_nontemporal_load(&partials[zoff + base]);
        l1 += __builtin_nontemporal_load(&partials[zoff + base + Dp]);
    }
    #pragma unroll
    for (int s = 1; s <= 4; s <<= 1) {
        mA += __shfl_xor(mA, s);
        m1 += __shfl_xor(m1, s);
        lA += __shfl_xor(lA, s);
        l1 += __shfl_xor(l1, s);
    }

    if (ok && sub == 0) {
        const float cnt = ws[4 + cls];
        const float m = (cls ? m1 : (mA - m1)) / cnt;
        const float l = (cls ? l1 : (lA - l1)) / cnt;
        out[1 + oidx]         = m;   // mus
        out[1 + 2 * D + oidx] = l;   // lsds
        float* p_tab = ws + 16;
        float* q_tab = p_tab + 2 * D;
        const float pv = 0.5f * expf(-2.f * l);
        p_tab[oidx] = pv;
        q_tab[oidx] = 2.f * pv * m;
    }
}

// per-row logp body; NT selects streaming (evict-first) z loads
template<bool NT>
__device__ __forceinline__ float row_logp(const float4* __restrict__ z4,
                                          const float4* __restrict__ p4,
                                          const float4* __restrict__ q4,
                                          int D4, int lane)
{
    float acc = 0.f;
    int i = lane;
    for (; i + 64 < D4; i += 128) {
        float4 zz0, zz1;
        if constexpr (NT) { zz0 = ldnt4(z4 + i); zz1 = ldnt4(z4 + i + 64); }
        else              { zz0 = z4[i];         zz1 = z4[i + 64]; }
        const float4 pp0 = p4[i];      const float4 pp1 = p4[i + 64];
        const float4 qq0 = q4[i];      const float4 qq1 = q4[i + 64];
        acc += zz0.x * (qq0.x - pp0.x * zz0.x);
        acc += zz0.y * (qq0.y - pp0.y * zz0.y);
        acc += zz0.z * (qq0.z - pp0.z * zz0.z);
        acc += zz0.w * (qq0.w - pp0.w * zz0.w);
        acc += zz1.x * (qq1.x - pp1.x * zz1.x);
        acc += zz1.y * (qq1.y - pp1.y * zz1.y);
        acc += zz1.z * (qq1.z - pp1.z * zz1.z);
        acc += zz1.w * (qq1.w - pp1.w * zz1.w);
    }
    for (; i < D4; i += 64) {
        float4 zz;
        if constexpr (NT) zz = ldnt4(z4 + i);
        else              zz = z4[i];
        const float4 pp = p4[i];
        const float4 qq = q4[i];
        acc += zz.x * (qq.x - pp.x * zz.x);
        acc += zz.y * (qq.y - pp.y * zz.y);
        acc += zz.z * (qq.z - pp.z * zz.z);
        acc += zz.w * (qq.w - pp.w * zz.w);
    }
    return acc;
}

__global__ __launch_bounds__(BLOCK) void k_logp(
    const float* __restrict__ z,
    const int*   __restrict__ target,
    const float* __restrict__ ws,
    float* __restrict__ logp_out,
    int N, int D)
{
    const int wave = threadIdx.x >> 6;
    const int lane = threadIdx.x & 63;
    const int n    = blockIdx.x * 4 + wave;
    const int D4   = D >> 2;
    if (n >= N) return;

    const int t = __builtin_amdgcn_readfirstlane(target[n]);
    const float4* z4 = reinterpret_cast<const float4*>(z) + (size_t)n * D4;
    const float4* p4 = reinterpret_cast<const float4*>(ws + 16) + (size_t)t * D4;
    const float4* q4 = p4 + 2 * D4;

    // first half of z non-temporal (R13 best-known configuration)
    float acc;
    if (n < (N >> 1)) acc = row_logp<true >(z4, p4, q4, D4, lane);
    else              acc = row_logp<false>(z4, p4, q4, D4, lane);

    #pragma unroll
    for (int m = 32; m >= 1; m >>= 1) acc += __shfl_xor(acc, m);
    if (lane == 0) logp_out[n] = acc;        // Bc added in k_finalize2
}

// epilogue: per-class Bc from mus/lsds, patch logp, class means, prior
__global__ __launch_bounds__(1024) void k_finalize2(
    const int*   __restrict__ target,
    const float* __restrict__ stats,
    float* __restrict__ out,
    int N, int D, int out_off)
{
    const int tid = threadIdx.x;
    const float* mus  = out + 1;
    const float* lsds = out + 1 + 2 * D;
    float* logp = out + 1 + 4 * D;

    // phase 1: Bc[cls] = sum_d ( -0.5*log2pi - l - 0.5*exp(-2l)*m^2 )
    float b0 = 0.f, b1 = 0.f;
    for (int idx = tid; idx < 2 * D; idx += 1024) {
        const float m = mus[idx];
        const float l = lsds[idx];
        const float b = -0.5f * LOG_2PI_F - l - 0.5f * expf(-2.f * l) * m * m;
        if (idx < D) b0 += b; else b1 += b;
    }
    __shared__ float s0[1024];
    __shared__ float s1[1024];
    s0[tid] = b0; s1[tid] = b1;
    __syncthreads();
    for (int off = 512; off > 0; off >>= 1) {
        if (tid < off) {
            s0[tid] += s0[tid + off];
            s1[tid] += s1[tid + off];
        }
        __syncthreads();
    }
    const float B0 = s0[0];
    const float B1 = s1[0];
    __syncthreads();

    // phase 2: patch logp with Bc, accumulate per-class sums
    float cA = 0.f, c1 = 0.f;
    for (int i = tid; i < N; i += 1024) {
        const int   t = target[i];
        const float v = logp[i] + (t ? B1 : B0);
        logp[i] = v;
        cA += v;
        if (t) c1 += v;
    }
    s0[tid] = cA; s1[tid] = c1;
    __syncthreads();
    for (int off = 512; off > 0; off >>= 1) {
        if (tid < off) {
            s0[tid] += s0[tid + off];
            s1[tid] += s1[tid + off];
        }
        __syncthreads();
    }
    if (tid == 0) {
        const float lp0 = (s0[0] - s1[0]) / stats[4];
        const float lp1 = s1[0] / stats[5];
        const float ld0 = stats[2] / stats[4];
        const float ld1 = stats[3] / stats[5];
        out[out_off]     = lp0;            // log_p_total[0]
        out[out_off + 1] = lp1;            // log_p_total[1]
        out[0] = 0.5f * ((lp0 + ld0) + (lp1 + ld1));  // prior_logprob
    }
}

extern "C" void kernel_launch(void* const* d_in, const int* in_sizes, int n_in,
                              void* d_out, int out_size, void* d_ws, size_t ws_size,
                              hipStream_t stream)
{
    const float* z      = (const float*)d_in[0];
    const float* mean   = (const float*)d_in[1];
    const float* log_sd = (const float*)d_in[2];
    const float* logdet = (const float*)d_in[3];
    const int*   target = (const int*)d_in[4];
    float* out = (float*)d_out;
    float* ws  = (float*)d_ws;

    const int N  = in_sizes[3];            // 8192
    const int D  = in_sizes[0] / N;        // 3072
    const int D4 = D >> 2;                 // 768
    const int Dp = D;                      // plane width

    size_t part0 = (size_t)(16 + 4 * D);
    part0 = (part0 + 255) & ~(size_t)255;

    // flat path parameters: 1536 blocks -> 512 rows/iter -> 512 slots
    const int FLAT_BLOCKS = 1536;
    const int SLOTS = FLAT_BLOCKS * BLOCK / 768;       // 512

    const bool flatOK =
        (D == 3072) && (N % SLOTS == 0) &&
        ((part0 + (size_t)2 * SLOTS * 2 * Dp) * sizeof(float) <= ws_size);

    float* partials = ws + part0;

    if (flatOK) {
        // pass 1: flat thread-linear column sums, one array per launch
        k_colsum3_flat<<<FLAT_BLOCKS, BLOCK, 0, stream>>>(
            mean,   target, logdet, partials, ws, N, 0);
        k_colsum3_flat<<<FLAT_BLOCKS, BLOCK, 0, stream>>>(
            log_sd, target, logdet, partials, ws, N, 1);

        const int nred = (2 * D + 31) / 32;
        k_reduce_finalize<<<nred, BLOCK, 0, stream>>>(partials, ws, out,
                                                      D, Dp, SLOTS);
    } else {
        int G = 512;
        while (G > 8 &&
               (part0 + (size_t)2 * G * 2 * Dp) * sizeof(float) > ws_size)
            G >>= 1;
        dim3 g1((D4 + BLOCK - 1) / BLOCK, G, 2);
        k_colsum_gen<<<g1, BLOCK, 0, stream>>>(mean, log_sd, target, logdet,
                                               partials, ws, N, D4, Dp, G);
        const int nred = (2 * D + 31) / 32;
        k_reduce_finalize<<<nred, BLOCK, 0, stream>>>(partials, ws, out,
                                                      D, Dp, G);
    }

    // pass 2: per-sample logp (half of z non-temporal — R13 config)
    float* logp_out = out + 1 + 4 * D;
    k_logp<<<(N + 3) / 4, BLOCK, 0, stream>>>(z, target, ws, logp_out, N, D);

    // epilogue: Bc + patch logp + class means + prior
    k_finalize2<<<1, 1024, 0, stream>>>(target, ws, out, N, D, 1 + 4 * D + N);
}

// Round 19
// 69.607 us; speedup vs baseline: 1.3986x; 1.3452x over previous
//
#include <hip/hip_runtime.h>

#define BLOCK 256
#define LOG_2PI_F 1.8378770664093453f

typedef float v4f __attribute__((ext_vector_type(4)));

// ws layout (float offsets):
//   0..7   : stats: [2] ld_sum0 [3] ld_sum1 [4] cnt0 [5] cnt1
//   16     : p_tab [2*D]   (= 0.5*exp(-2*lsd))
//   16+2D  : q_tab [2*D]   (= 2*p*mu)
//   PART0  : partials [2(z)][G][2][Dp]  (plane 0 = sumAll, 1 = sumC1), Dp = D
//
// out layout: [0] prior | [1,1+2D) mus | [1+2D,1+4D) lsds |
//             [1+4D,1+4D+N) logp | [1+4D+N, +2) log_p_total
//
// G = 128 (was 512): partials shrink 25.2 -> 6.3 MB each way. Colsum read
// rate is pinned at ~3 TB/s for ANY shape (R7-R18 ledger); the only
// remaining slack was secondary traffic volume.

__device__ __forceinline__ void acc2(float2& s, const float2 d) {
    s.x += d.x; s.y += d.y;
}
__device__ __forceinline__ void fma2(float2& s, const float2 d, const float w) {
    s.x = fmaf(d.x, w, s.x); s.y = fmaf(d.y, w, s.y);
}

// non-temporal 16B load (evict-first hint; data used once)
__device__ __forceinline__ float4 ldnt4(const float4* p) {
    v4f t = __builtin_nontemporal_load((const v4f*)p);
    float4 r; r.x = t.x; r.y = t.y; r.z = t.z; r.w = t.w;
    return r;
}

// shared stats helper: counts + per-class logdet sums (run by one block)
__device__ void do_stats(const int* __restrict__ target,
                         const float* __restrict__ logdet,
                         float* __restrict__ stats, int N)
{
    const int tid = threadIdx.x;
    float ldA = 0.f, ld1 = 0.f;
    int   c1  = 0;
    if ((N & 3) == 0) {
        const int4*   t4 = reinterpret_cast<const int4*>(target);
        const float4* l4 = reinterpret_cast<const float4*>(logdet);
        for (int i = tid; i < (N >> 2); i += BLOCK) {
            const int4   t = t4[i];
            const float4 v = l4[i];
            ldA += v.x + v.y + v.z + v.w;
            if (t.x) { c1++; ld1 += v.x; }
            if (t.y) { c1++; ld1 += v.y; }
            if (t.z) { c1++; ld1 += v.z; }
            if (t.w) { c1++; ld1 += v.w; }
        }
    } else {
        for (int n = tid; n < N; n += BLOCK) {
            const float v = logdet[n];
            ldA += v;
            if (target[n]) { c1++; ld1 += v; }
        }
    }
    __shared__ float sB[BLOCK], sC[BLOCK];
    __shared__ int   sI[BLOCK];
    sB[tid] = ldA; sC[tid] = ld1; sI[tid] = c1;
    __syncthreads();
    for (int off = BLOCK / 2; off > 0; off >>= 1) {
        if (tid < off) {
            sB[tid] += sB[tid + off];
            sC[tid] += sC[tid + off];
            sI[tid] += sI[tid + off];
        }
        __syncthreads();
    }
    if (tid == 0) {
        stats[2] = sB[0] - sC[0];          // ld_sum0
        stats[3] = sC[0];                  // ld_sum1
        stats[4] = (float)(N - sI[0]);     // cnt0
        stats[5] = (float)sI[0];           // cnt1
    }
}

// fast path (D == 3072): R13's max-occupancy float2 streaming, G=128.
// grid (G, 2 col-halves, 2 arrays); block (b,h,z) covers columns
// [h*1536,(h+1)*1536) of rows {b, b+G, ...}.
__global__ __launch_bounds__(BLOCK) void k_colsum3(
    const float* __restrict__ mean,
    const float* __restrict__ log_sd,
    const int*   __restrict__ target,
    const float* __restrict__ logdet,
    float* __restrict__ partials,
    float* __restrict__ stats,
    int N, int G)
{
    const int tid  = threadIdx.x;
    const int wave = tid >> 6;
    const int lane = tid & 63;
    const int b    = blockIdx.x;            // row slot, 0..G-1
    const int h    = blockIdx.y;            // column half
    const int z    = blockIdx.z;            // array select
    const int D2   = 1536;                  // 3072 / 2 (float2 per row)

    const float2* src2 =
        reinterpret_cast<const float2*>(z == 0 ? mean : log_sd);
    const int base2 = h * 768 + wave * 192 + lane;
    const float2* p = src2 + (size_t)b * D2 + base2;
    const size_t rstep = (size_t)G * D2;

    const int nk = (b < N) ? ((N - 1 - b) / G + 1) : 0;

    __shared__ float wrow[64];
    for (int i = tid; i < nk && i < 64; i += BLOCK)
        wrow[i] = target[b + i * G] ? 1.f : 0.f;
    __syncthreads();

    float2 A0 = make_float2(0.f, 0.f);
    float2 A1 = make_float2(0.f, 0.f);
    float2 A2 = make_float2(0.f, 0.f);
    float2 C0 = make_float2(0.f, 0.f);
    float2 C1 = make_float2(0.f, 0.f);
    float2 C2 = make_float2(0.f, 0.f);

    int k = 0;
    for (; k + 2 <= nk; k += 2) {
        const float2* pa = p + (size_t)k * rstep;
        const float2* pb = pa + rstep;
        const float2 a0 = pa[0];
        const float2 a1 = pa[64];
        const float2 a2 = pa[128];
        const float2 b0 = pb[0];
        const float2 b1 = pb[64];
        const float2 b2 = pb[128];
        const float wa = wrow[k];
        const float wb = wrow[k + 1];
        acc2(A0, a0); fma2(C0, a0, wa);
        acc2(A1, a1); fma2(C1, a1, wa);
        acc2(A2, a2); fma2(C2, a2, wa);
        acc2(A0, b0); fma2(C0, b0, wb);
        acc2(A1, b1); fma2(C1, b1, wb);
        acc2(A2, b2); fma2(C2, b2, wb);
    }
    if (k < nk) {
        const float2* pa = p + (size_t)k * rstep;
        const float2 a0 = pa[0];
        const float2 a1 = pa[64];
        const float2 a2 = pa[128];
        const float w = wrow[k];
        acc2(A0, a0); fma2(C0, a0, w);
        acc2(A1, a1); fma2(C1, a1, w);
        acc2(A2, a2); fma2(C2, a2, w);
    }

    float* sbase = partials + ((size_t)z * G + b) * (2 * 3072);
    float2* pl0 = reinterpret_cast<float2*>(sbase);          // plane sumAll
    float2* pl1 = reinterpret_cast<float2*>(sbase + 3072);   // plane sumC1
    pl0[base2]       = A0;
    pl0[base2 + 64]  = A1;
    pl0[base2 + 128] = A2;
    pl1[base2]       = C0;
    pl1[base2 + 64]  = C1;
    pl1[base2 + 128] = C2;

    if (b == 0 && h == 0 && z == 0) do_stats(target, logdet, stats, N);
}

// generic fallback (any D): round-robin rows, column-group blocks
__global__ __launch_bounds__(BLOCK, 4) void k_colsum_gen(
    const float* __restrict__ mean,
    const float* __restrict__ log_sd,
    const int*   __restrict__ target,
    const float* __restrict__ logdet,
    float* __restrict__ partials,
    float* __restrict__ stats,
    int N, int D4, int Dp, int G)
{
    const int c4 = blockIdx.x * BLOCK + threadIdx.x;
    const bool colOK = (c4 < D4);
    const int by = blockIdx.y;

    const float4* src4 =
        reinterpret_cast<const float4*>(blockIdx.z == 0 ? mean : log_sd);
    const float4* p = src4 + (size_t)by * D4 + (colOK ? c4 : 0);
    const size_t rstep = (size_t)G * D4;
    const int nk = (by < N) ? ((N - 1 - by) / G + 1) : 0;

    float4 sA = make_float4(0.f,0.f,0.f,0.f);
    float4 s1 = make_float4(0.f,0.f,0.f,0.f);
    for (int k = 0; k < nk; ++k) {
        const float w = target[by + k * G] ? 1.f : 0.f;
        const float4 d = p[(size_t)k * rstep];
        sA.x += d.x; sA.y += d.y; sA.z += d.z; sA.w += d.w;
        s1.x = fmaf(d.x, w, s1.x);
        s1.y = fmaf(d.y, w, s1.y);
        s1.z = fmaf(d.z, w, s1.z);
        s1.w = fmaf(d.w, w, s1.w);
    }

    if (colOK) {
        float* base = partials +
            ((size_t)blockIdx.z * G + by) * (2 * (size_t)Dp);
        reinterpret_cast<float4*>(base)[c4]      = sA;
        reinterpret_cast<float4*>(base + Dp)[c4] = s1;
    }
    if (blockIdx.x == 0 && by == 0 && blockIdx.z == 0)
        do_stats(target, logdet, stats, N);
}

// reduce partials over G slots; NT loads (partials dead after this)
__global__ __launch_bounds__(BLOCK) void k_reduce_finalize(
    const float* __restrict__ partials,
    float* __restrict__ ws,
    float* __restrict__ out,
    int D, int Dp, int G)
{
    const int sub  = threadIdx.x & 7;
    const int slot = threadIdx.x >> 3;                 // 0..31
    const int oidx = blockIdx.x * 32 + slot;           // [0, 2*D)
    const bool ok  = (oidx < 2 * D);
    const int cls = ok ? (oidx / D) : 0;
    const int col = ok ? (oidx - cls * D) : 0;

    const size_t strideBY = 2 * (size_t)Dp;
    const size_t zoff     = (size_t)G * strideBY;
    const int per = G >> 3;

    float mA = 0.f, m1 = 0.f, lA = 0.f, l1 = 0.f;
    for (int j = 0; j < per; ++j) {
        const size_t base = (size_t)(sub * per + j) * strideBY + col;
        mA += __builtin_nontemporal_load(&partials[base]);
        m1 += __builtin_nontemporal_load(&partials[base + Dp]);
        lA += __builtin_nontemporal_load(&partials[zoff + base]);
        l1 += __builtin_nontemporal_load(&partials[zoff + base + Dp]);
    }
    #pragma unroll
    for (int s = 1; s <= 4; s <<= 1) {
        mA += __shfl_xor(mA, s);
        m1 += __shfl_xor(m1, s);
        lA += __shfl_xor(lA, s);
        l1 += __shfl_xor(l1, s);
    }

    if (ok && sub == 0) {
        const float cnt = ws[4 + cls];
        const float m = (cls ? m1 : (mA - m1)) / cnt;
        const float l = (cls ? l1 : (lA - l1)) / cnt;
        out[1 + oidx]         = m;   // mus
        out[1 + 2 * D + oidx] = l;   // lsds
        float* p_tab = ws + 16;
        float* q_tab = p_tab + 2 * D;
        const float pv = 0.5f * expf(-2.f * l);
        p_tab[oidx] = pv;
        q_tab[oidx] = 2.f * pv * m;
    }
}

// per-row logp body; NT selects streaming (evict-first) z loads
template<bool NT>
__device__ __forceinline__ float row_logp(const float4* __restrict__ z4,
                                          const float4* __restrict__ p4,
                                          const float4* __restrict__ q4,
                                          int D4, int lane)
{
    float acc = 0.f;
    int i = lane;
    for (; i + 64 < D4; i += 128) {
        float4 zz0, zz1;
        if constexpr (NT) { zz0 = ldnt4(z4 + i); zz1 = ldnt4(z4 + i + 64); }
        else              { zz0 = z4[i];         zz1 = z4[i + 64]; }
        const float4 pp0 = p4[i];      const float4 pp1 = p4[i + 64];
        const float4 qq0 = q4[i];      const float4 qq1 = q4[i + 64];
        acc += zz0.x * (qq0.x - pp0.x * zz0.x);
        acc += zz0.y * (qq0.y - pp0.y * zz0.y);
        acc += zz0.z * (qq0.z - pp0.z * zz0.z);
        acc += zz0.w * (qq0.w - pp0.w * zz0.w);
        acc += zz1.x * (qq1.x - pp1.x * zz1.x);
        acc += zz1.y * (qq1.y - pp1.y * zz1.y);
        acc += zz1.z * (qq1.z - pp1.z * zz1.z);
        acc += zz1.w * (qq1.w - pp1.w * zz1.w);
    }
    for (; i < D4; i += 64) {
        float4 zz;
        if constexpr (NT) zz = ldnt4(z4 + i);
        else              zz = z4[i];
        const float4 pp = p4[i];
        const float4 qq = q4[i];
        acc += zz.x * (qq.x - pp.x * zz.x);
        acc += zz.y * (qq.y - pp.y * zz.y);
        acc += zz.z * (qq.z - pp.z * zz.z);
        acc += zz.w * (qq.w - pp.w * zz.w);
    }
    return acc;
}

__global__ __launch_bounds__(BLOCK) void k_logp(
    const float* __restrict__ z,
    const int*   __restrict__ target,
    const float* __restrict__ ws,
    float* __restrict__ logp_out,
    int N, int D)
{
    const int wave = threadIdx.x >> 6;
    const int lane = threadIdx.x & 63;
    const int n    = blockIdx.x * 4 + wave;
    const int D4   = D >> 2;
    if (n >= N) return;

    const int t = __builtin_amdgcn_readfirstlane(target[n]);
    const float4* z4 = reinterpret_cast<const float4*>(z) + (size_t)n * D4;
    const float4* p4 = reinterpret_cast<const float4*>(ws + 16) + (size_t)t * D4;
    const float4* q4 = p4 + 2 * D4;

    // first half of z non-temporal (R13 best-known configuration)
    float acc;
    if (n < (N >> 1)) acc = row_logp<true >(z4, p4, q4, D4, lane);
    else              acc = row_logp<false>(z4, p4, q4, D4, lane);

    #pragma unroll
    for (int m = 32; m >= 1; m >>= 1) acc += __shfl_xor(acc, m);
    if (lane == 0) logp_out[n] = acc;        // Bc added in k_finalize2
}

// epilogue: per-class Bc from mus/lsds, patch logp, class means, prior
__global__ __launch_bounds__(1024) void k_finalize2(
    const int*   __restrict__ target,
    const float* __restrict__ stats,
    float* __restrict__ out,
    int N, int D, int out_off)
{
    const int tid = threadIdx.x;
    const float* mus  = out + 1;
    const float* lsds = out + 1 + 2 * D;
    float* logp = out + 1 + 4 * D;

    // phase 1: Bc[cls] = sum_d ( -0.5*log2pi - l - 0.5*exp(-2l)*m^2 )
    float b0 = 0.f, b1 = 0.f;
    for (int idx = tid; idx < 2 * D; idx += 1024) {
        const float m = mus[idx];
        const float l = lsds[idx];
        const float b = -0.5f * LOG_2PI_F - l - 0.5f * expf(-2.f * l) * m * m;
        if (idx < D) b0 += b; else b1 += b;
    }
    __shared__ float s0[1024];
    __shared__ float s1[1024];
    s0[tid] = b0; s1[tid] = b1;
    __syncthreads();
    for (int off = 512; off > 0; off >>= 1) {
        if (tid < off) {
            s0[tid] += s0[tid + off];
            s1[tid] += s1[tid + off];
        }
        __syncthreads();
    }
    const float B0 = s0[0];
    const float B1 = s1[0];
    __syncthreads();

    // phase 2: patch logp with Bc, accumulate per-class sums
    float cA = 0.f, c1 = 0.f;
    for (int i = tid; i < N; i += 1024) {
        const int   t = target[i];
        const float v = logp[i] + (t ? B1 : B0);
        logp[i] = v;
        cA += v;
        if (t) c1 += v;
    }
    s0[tid] = cA; s1[tid] = c1;
    __syncthreads();
    for (int off = 512; off > 0; off >>= 1) {
        if (tid < off) {
            s0[tid] += s0[tid + off];
            s1[tid] += s1[tid + off];
        }
        __syncthreads();
    }
    if (tid == 0) {
        const float lp0 = (s0[0] - s1[0]) / stats[4];
        const float lp1 = s1[0] / stats[5];
        const float ld0 = stats[2] / stats[4];
        const float ld1 = stats[3] / stats[5];
        out[out_off]     = lp0;            // log_p_total[0]
        out[out_off + 1] = lp1;            // log_p_total[1]
        out[0] = 0.5f * ((lp0 + ld0) + (lp1 + ld1));  // prior_logprob
    }
}

extern "C" void kernel_launch(void* const* d_in, const int* in_sizes, int n_in,
                              void* d_out, int out_size, void* d_ws, size_t ws_size,
                              hipStream_t stream)
{
    const float* z      = (const float*)d_in[0];
    const float* mean   = (const float*)d_in[1];
    const float* log_sd = (const float*)d_in[2];
    const float* logdet = (const float*)d_in[3];
    const int*   target = (const int*)d_in[4];
    float* out = (float*)d_out;
    float* ws  = (float*)d_ws;

    const int N  = in_sizes[3];            // 8192
    const int D  = in_sizes[0] / N;        // 3072
    const int D4 = D >> 2;                 // 768
    const int Dp = D;                      // plane width

    size_t part0 = (size_t)(16 + 4 * D);
    part0 = (part0 + 255) & ~(size_t)255;

    // G = 128 -> partials 6.3 MB (was 25.2 at G=512); rate is occupancy-
    // invariant (R5-R12), so fewer slots only cut secondary traffic
    int G = 128;
    while (G > 8 &&
           (part0 + (size_t)2 * G * 2 * Dp) * sizeof(float) > ws_size)
        G >>= 1;

    float* partials = ws + part0;

    const int nkMax = (N + G - 1) / G;

    // pass 1: max-occupancy per-class column partial sums
    if (D == 3072 && nkMax <= 64) {
        dim3 g1(G, 2, 2);
        k_colsum3<<<g1, BLOCK, 0, stream>>>(mean, log_sd, target, logdet,
                                            partials, ws, N, G);
    } else {
        dim3 g1((D4 + BLOCK - 1) / BLOCK, G, 2);
        k_colsum_gen<<<g1, BLOCK, 0, stream>>>(mean, log_sd, target, logdet,
                                               partials, ws, N, D4, Dp, G);
    }

    // reduce partials (NT) + finalize class params + build p/q tables
    const int nred = (2 * D + 31) / 32;
    k_reduce_finalize<<<nred, BLOCK, 0, stream>>>(partials, ws, out, D, Dp, G);

    // pass 2: per-sample logp (half of z non-temporal — R13 config)
    float* logp_out = out + 1 + 4 * D;
    k_logp<<<(N + 3) / 4, BLOCK, 0, stream>>>(z, target, ws, logp_out, N, D);

    // epilogue: Bc + patch logp + class means + prior
    k_finalize2<<<1, 1024, 0, stream>>>(target, ws, out, N, D, 1 + 4 * D + N);
}

// Round 20
// 67.334 us; speedup vs baseline: 1.4458x; 1.0337x over previous
//
#include <hip/hip_runtime.h>

#define BLOCK 256
#define LOG_2PI_F 1.8378770664093453f

typedef float v4f __attribute__((ext_vector_type(4)));

// ws layout (float offsets):
//   0..7   : stats: [2] ld_sum0 [3] ld_sum1 [4] cnt0 [5] cnt1
//   16     : p_tab [2*D]   (= 0.5*exp(-2*lsd))
//   16+2D  : q_tab [2*D]   (= 2*p*mu)
//   PART0  : partials [2(z)][G][2][Dp]  (plane 0 = sumAll, 1 = sumC1), Dp = D
//
// out layout: [0] prior | [1,1+2D) mus | [1+2D,1+4D) lsds |
//             [1+4D,1+4D+N) logp | [1+4D+N, +2) log_p_total
//
// G = 64 (R19 used 128): partials round-trip 12.6 -> 6.3 MB. Colsum read
// rate is shape/occupancy-invariant (~3-3.9 TB/s, R5-R18 ledger); the only
// lever that moved total time was secondary-traffic volume (R19: -21 us).

__device__ __forceinline__ void acc2(float2& s, const float2 d) {
    s.x += d.x; s.y += d.y;
}
__device__ __forceinline__ void fma2(float2& s, const float2 d, const float w) {
    s.x = fmaf(d.x, w, s.x); s.y = fmaf(d.y, w, s.y);
}

// non-temporal 16B load (evict-first hint; data used once)
__device__ __forceinline__ float4 ldnt4(const float4* p) {
    v4f t = __builtin_nontemporal_load((const v4f*)p);
    float4 r; r.x = t.x; r.y = t.y; r.z = t.z; r.w = t.w;
    return r;
}

// shared stats helper: counts + per-class logdet sums (run by one block)
__device__ void do_stats(const int* __restrict__ target,
                         const float* __restrict__ logdet,
                         float* __restrict__ stats, int N)
{
    const int tid = threadIdx.x;
    float ldA = 0.f, ld1 = 0.f;
    int   c1  = 0;
    if ((N & 3) == 0) {
        const int4*   t4 = reinterpret_cast<const int4*>(target);
        const float4* l4 = reinterpret_cast<const float4*>(logdet);
        for (int i = tid; i < (N >> 2); i += BLOCK) {
            const int4   t = t4[i];
            const float4 v = l4[i];
            ldA += v.x + v.y + v.z + v.w;
            if (t.x) { c1++; ld1 += v.x; }
            if (t.y) { c1++; ld1 += v.y; }
            if (t.z) { c1++; ld1 += v.z; }
            if (t.w) { c1++; ld1 += v.w; }
        }
    } else {
        for (int n = tid; n < N; n += BLOCK) {
            const float v = logdet[n];
            ldA += v;
            if (target[n]) { c1++; ld1 += v; }
        }
    }
    __shared__ float sB[BLOCK], sC[BLOCK];
    __shared__ int   sI[BLOCK];
    sB[tid] = ldA; sC[tid] = ld1; sI[tid] = c1;
    __syncthreads();
    for (int off = BLOCK / 2; off > 0; off >>= 1) {
        if (tid < off) {
            sB[tid] += sB[tid + off];
            sC[tid] += sC[tid + off];
            sI[tid] += sI[tid + off];
        }
        __syncthreads();
    }
    if (tid == 0) {
        stats[2] = sB[0] - sC[0];          // ld_sum0
        stats[3] = sC[0];                  // ld_sum1
        stats[4] = (float)(N - sI[0]);     // cnt0
        stats[5] = (float)sI[0];           // cnt1
    }
}

// fast path (D == 3072): max-occupancy float2 streaming (R13/R19 shape).
// grid (G, 2 col-halves, 2 arrays); block (b,h,z) covers columns
// [h*1536,(h+1)*1536) of rows {b, b+G, ...}. nk up to 128 rows/block.
__global__ __launch_bounds__(BLOCK) void k_colsum3(
    const float* __restrict__ mean,
    const float* __restrict__ log_sd,
    const int*   __restrict__ target,
    const float* __restrict__ logdet,
    float* __restrict__ partials,
    float* __restrict__ stats,
    int N, int G)
{
    const int tid  = threadIdx.x;
    const int wave = tid >> 6;
    const int lane = tid & 63;
    const int b    = blockIdx.x;            // row slot, 0..G-1
    const int h    = blockIdx.y;            // column half
    const int z    = blockIdx.z;            // array select
    const int D2   = 1536;                  // 3072 / 2 (float2 per row)

    const float2* src2 =
        reinterpret_cast<const float2*>(z == 0 ? mean : log_sd);
    const int base2 = h * 768 + wave * 192 + lane;
    const float2* p = src2 + (size_t)b * D2 + base2;
    const size_t rstep = (size_t)G * D2;

    const int nk = (b < N) ? ((N - 1 - b) / G + 1) : 0;

    __shared__ float wrow[128];
    for (int i = tid; i < nk && i < 128; i += BLOCK)
        wrow[i] = target[b + i * G] ? 1.f : 0.f;
    __syncthreads();

    float2 A0 = make_float2(0.f, 0.f);
    float2 A1 = make_float2(0.f, 0.f);
    float2 A2 = make_float2(0.f, 0.f);
    float2 C0 = make_float2(0.f, 0.f);
    float2 C1 = make_float2(0.f, 0.f);
    float2 C2 = make_float2(0.f, 0.f);

    int k = 0;
    for (; k + 2 <= nk; k += 2) {
        const float2* pa = p + (size_t)k * rstep;
        const float2* pb = pa + rstep;
        const float2 a0 = pa[0];
        const float2 a1 = pa[64];
        const float2 a2 = pa[128];
        const float2 b0 = pb[0];
        const float2 b1 = pb[64];
        const float2 b2 = pb[128];
        const float wa = wrow[k];
        const float wb = wrow[k + 1];
        acc2(A0, a0); fma2(C0, a0, wa);
        acc2(A1, a1); fma2(C1, a1, wa);
        acc2(A2, a2); fma2(C2, a2, wa);
        acc2(A0, b0); fma2(C0, b0, wb);
        acc2(A1, b1); fma2(C1, b1, wb);
        acc2(A2, b2); fma2(C2, b2, wb);
    }
    if (k < nk) {
        const float2* pa = p + (size_t)k * rstep;
        const float2 a0 = pa[0];
        const float2 a1 = pa[64];
        const float2 a2 = pa[128];
        const float w = wrow[k];
        acc2(A0, a0); fma2(C0, a0, w);
        acc2(A1, a1); fma2(C1, a1, w);
        acc2(A2, a2); fma2(C2, a2, w);
    }

    float* sbase = partials + ((size_t)z * G + b) * (2 * 3072);
    float2* pl0 = reinterpret_cast<float2*>(sbase);          // plane sumAll
    float2* pl1 = reinterpret_cast<float2*>(sbase + 3072);   // plane sumC1
    pl0[base2]       = A0;
    pl0[base2 + 64]  = A1;
    pl0[base2 + 128] = A2;
    pl1[base2]       = C0;
    pl1[base2 + 64]  = C1;
    pl1[base2 + 128] = C2;

    if (b == 0 && h == 0 && z == 0) do_stats(target, logdet, stats, N);
}

// generic fallback (any D): round-robin rows, column-group blocks
__global__ __launch_bounds__(BLOCK, 4) void k_colsum_gen(
    const float* __restrict__ mean,
    const float* __restrict__ log_sd,
    const int*   __restrict__ target,
    const float* __restrict__ logdet,
    float* __restrict__ partials,
    float* __restrict__ stats,
    int N, int D4, int Dp, int G)
{
    const int c4 = blockIdx.x * BLOCK + threadIdx.x;
    const bool colOK = (c4 < D4);
    const int by = blockIdx.y;

    const float4* src4 =
        reinterpret_cast<const float4*>(blockIdx.z == 0 ? mean : log_sd);
    const float4* p = src4 + (size_t)by * D4 + (colOK ? c4 : 0);
    const size_t rstep = (size_t)G * D4;
    const int nk = (by < N) ? ((N - 1 - by) / G + 1) : 0;

    float4 sA = make_float4(0.f,0.f,0.f,0.f);
    float4 s1 = make_float4(0.f,0.f,0.f,0.f);
    for (int k = 0; k < nk; ++k) {
        const float w = target[by + k * G] ? 1.f : 0.f;
        const float4 d = p[(size_t)k * rstep];
        sA.x += d.x; sA.y += d.y; sA.z += d.z; sA.w += d.w;
        s1.x = fmaf(d.x, w, s1.x);
        s1.y = fmaf(d.y, w, s1.y);
        s1.z = fmaf(d.z, w, s1.z);
        s1.w = fmaf(d.w, w, s1.w);
    }

    if (colOK) {
        float* base = partials +
            ((size_t)blockIdx.z * G + by) * (2 * (size_t)Dp);
        reinterpret_cast<float4*>(base)[c4]      = sA;
        reinterpret_cast<float4*>(base + Dp)[c4] = s1;
    }
    if (blockIdx.x == 0 && by == 0 && blockIdx.z == 0)
        do_stats(target, logdet, stats, N);
}

// reduce partials over G slots; NT loads (partials dead after this)
__global__ __launch_bounds__(BLOCK) void k_reduce_finalize(
    const float* __restrict__ partials,
    float* __restrict__ ws,
    float* __restrict__ out,
    int D, int Dp, int G)
{
    const int sub  = threadIdx.x & 7;
    const int slot = threadIdx.x >> 3;                 // 0..31
    const int oidx = blockIdx.x * 32 + slot;           // [0, 2*D)
    const bool ok  = (oidx < 2 * D);
    const int cls = ok ? (oidx / D) : 0;
    const int col = ok ? (oidx - cls * D) : 0;

    const size_t strideBY = 2 * (size_t)Dp;
    const size_t zoff     = (size_t)G * strideBY;
    const int per = G >> 3;

    float mA = 0.f, m1 = 0.f, lA = 0.f, l1 = 0.f;
    for (int j = 0; j < per; ++j) {
        const size_t base = (size_t)(sub * per + j) * strideBY + col;
        mA += __builtin_nontemporal_load(&partials[base]);
        m1 += __builtin_nontemporal_load(&partials[base + Dp]);
        lA += __builtin_nontemporal_load(&partials[zoff + base]);
        l1 += __builtin_nontemporal_load(&partials[zoff + base + Dp]);
    }
    #pragma unroll
    for (int s = 1; s <= 4; s <<= 1) {
        mA += __shfl_xor(mA, s);
        m1 += __shfl_xor(m1, s);
        lA += __shfl_xor(lA, s);
        l1 += __shfl_xor(l1, s);
    }

    if (ok && sub == 0) {
        const float cnt = ws[4 + cls];
        const float m = (cls ? m1 : (mA - m1)) / cnt;
        const float l = (cls ? l1 : (lA - l1)) / cnt;
        out[1 + oidx]         = m;   // mus
        out[1 + 2 * D + oidx] = l;   // lsds
        float* p_tab = ws + 16;
        float* q_tab = p_tab + 2 * D;
        const float pv = 0.5f * expf(-2.f * l);
        p_tab[oidx] = pv;
        q_tab[oidx] = 2.f * pv * m;
    }
}

// per-row logp body; NT selects streaming (evict-first) z loads
template<bool NT>
__device__ __forceinline__ float row_logp(const float4* __restrict__ z4,
                                          const float4* __restrict__ p4,
                                          const float4* __restrict__ q4,
                                          int D4, int lane)
{
    float acc = 0.f;
    int i = lane;
    for (; i + 64 < D4; i += 128) {
        float4 zz0, zz1;
        if constexpr (NT) { zz0 = ldnt4(z4 + i); zz1 = ldnt4(z4 + i + 64); }
        else              { zz0 = z4[i];         zz1 = z4[i + 64]; }
        const float4 pp0 = p4[i];      const float4 pp1 = p4[i + 64];
        const float4 qq0 = q4[i];      const float4 qq1 = q4[i + 64];
        acc += zz0.x * (qq0.x - pp0.x * zz0.x);
        acc += zz0.y * (qq0.y - pp0.y * zz0.y);
        acc += zz0.z * (qq0.z - pp0.z * zz0.z);
        acc += zz0.w * (qq0.w - pp0.w * zz0.w);
        acc += zz1.x * (qq1.x - pp1.x * zz1.x);
        acc += zz1.y * (qq1.y - pp1.y * zz1.y);
        acc += zz1.z * (qq1.z - pp1.z * zz1.z);
        acc += zz1.w * (qq1.w - pp1.w * zz1.w);
    }
    for (; i < D4; i += 64) {
        float4 zz;
        if constexpr (NT) zz = ldnt4(z4 + i);
        else              zz = z4[i];
        const float4 pp = p4[i];
        const float4 qq = q4[i];
        acc += zz.x * (qq.x - pp.x * zz.x);
        acc += zz.y * (qq.y - pp.y * zz.y);
        acc += zz.z * (qq.z - pp.z * zz.z);
        acc += zz.w * (qq.w - pp.w * zz.w);
    }
    return acc;
}

__global__ __launch_bounds__(BLOCK) void k_logp(
    const float* __restrict__ z,
    const int*   __restrict__ target,
    const float* __restrict__ ws,
    float* __restrict__ logp_out,
    int N, int D)
{
    const int wave = threadIdx.x >> 6;
    const int lane = threadIdx.x & 63;
    const int n    = blockIdx.x * 4 + wave;
    const int D4   = D >> 2;
    if (n >= N) return;

    const int t = __builtin_amdgcn_readfirstlane(target[n]);
    const float4* z4 = reinterpret_cast<const float4*>(z) + (size_t)n * D4;
    const float4* p4 = reinterpret_cast<const float4*>(ws + 16) + (size_t)t * D4;
    const float4* q4 = p4 + 2 * D4;

    // first half of z non-temporal (R13 best-known configuration)
    float acc;
    if (n < (N >> 1)) acc = row_logp<true >(z4, p4, q4, D4, lane);
    else              acc = row_logp<false>(z4, p4, q4, D4, lane);

    #pragma unroll
    for (int m = 32; m >= 1; m >>= 1) acc += __shfl_xor(acc, m);
    if (lane == 0) logp_out[n] = acc;        // Bc added in k_finalize2
}

// epilogue: per-class Bc from mus/lsds, patch logp, class means, prior
__global__ __launch_bounds__(1024) void k_finalize2(
    const int*   __restrict__ target,
    const float* __restrict__ stats,
    float* __restrict__ out,
    int N, int D, int out_off)
{
    const int tid = threadIdx.x;
    const float* mus  = out + 1;
    const float* lsds = out + 1 + 2 * D;
    float* logp = out + 1 + 4 * D;

    // phase 1: Bc[cls] = sum_d ( -0.5*log2pi - l - 0.5*exp(-2l)*m^2 )
    float b0 = 0.f, b1 = 0.f;
    for (int idx = tid; idx < 2 * D; idx += 1024) {
        const float m = mus[idx];
        const float l = lsds[idx];
        const float b = -0.5f * LOG_2PI_F - l - 0.5f * expf(-2.f * l) * m * m;
        if (idx < D) b0 += b; else b1 += b;
    }
    __shared__ float s0[1024];
    __shared__ float s1[1024];
    s0[tid] = b0; s1[tid] = b1;
    __syncthreads();
    for (int off = 512; off > 0; off >>= 1) {
        if (tid < off) {
            s0[tid] += s0[tid + off];
            s1[tid] += s1[tid + off];
        }
        __syncthreads();
    }
    const float B0 = s0[0];
    const float B1 = s1[0];
    __syncthreads();

    // phase 2: patch logp with Bc, accumulate per-class sums
    float cA = 0.f, c1 = 0.f;
    for (int i = tid; i < N; i += 1024) {
        const int   t = target[i];
        const float v = logp[i] + (t ? B1 : B0);
        logp[i] = v;
        cA += v;
        if (t) c1 += v;
    }
    s0[tid] = cA; s1[tid] = c1;
    __syncthreads();
    for (int off = 512; off > 0; off >>= 1) {
        if (tid < off) {
            s0[tid] += s0[tid + off];
            s1[tid] += s1[tid + off];
        }
        __syncthreads();
    }
    if (tid == 0) {
        const float lp0 = (s0[0] - s1[0]) / stats[4];
        const float lp1 = s1[0] / stats[5];
        const float ld0 = stats[2] / stats[4];
        const float ld1 = stats[3] / stats[5];
        out[out_off]     = lp0;            // log_p_total[0]
        out[out_off + 1] = lp1;            // log_p_total[1]
        out[0] = 0.5f * ((lp0 + ld0) + (lp1 + ld1));  // prior_logprob
    }
}

extern "C" void kernel_launch(void* const* d_in, const int* in_sizes, int n_in,
                              void* d_out, int out_size, void* d_ws, size_t ws_size,
                              hipStream_t stream)
{
    const float* z      = (const float*)d_in[0];
    const float* mean   = (const float*)d_in[1];
    const float* log_sd = (const float*)d_in[2];
    const float* logdet = (const float*)d_in[3];
    const int*   target = (const int*)d_in[4];
    float* out = (float*)d_out;
    float* ws  = (float*)d_ws;

    const int N  = in_sizes[3];            // 8192
    const int D  = in_sizes[0] / N;        // 3072
    const int D4 = D >> 2;                 // 768
    const int Dp = D;                      // plane width

    size_t part0 = (size_t)(16 + 4 * D);
    part0 = (part0 + 255) & ~(size_t)255;

    // G = 64 -> partials 3.15 MB each way (R19 had 6.3 at G=128)
    int G = 64;
    while (G > 8 &&
           (part0 + (size_t)2 * G * 2 * Dp) * sizeof(float) > ws_size)
        G >>= 1;

    float* partials = ws + part0;

    const int nkMax = (N + G - 1) / G;

    // pass 1: per-class column partial sums
    if (D == 3072 && nkMax <= 128) {
        dim3 g1(G, 2, 2);
        k_colsum3<<<g1, BLOCK, 0, stream>>>(mean, log_sd, target, logdet,
                                            partials, ws, N, G);
    } else {
        dim3 g1((D4 + BLOCK - 1) / BLOCK, G, 2);
        k_colsum_gen<<<g1, BLOCK, 0, stream>>>(mean, log_sd, target, logdet,
                                               partials, ws, N, D4, Dp, G);
    }

    // reduce partials (NT) + finalize class params + build p/q tables
    const int nred = (2 * D + 31) / 32;
    k_reduce_finalize<<<nred, BLOCK, 0, stream>>>(partials, ws, out, D, Dp, G);

    // pass 2: per-sample logp (half of z non-temporal — R13 config)
    float* logp_out = out + 1 + 4 * D;
    k_logp<<<(N + 3) / 4, BLOCK, 0, stream>>>(z, target, ws, logp_out, N, D);

    // epilogue: Bc + patch logp + class means + prior
    k_finalize2<<<1, 1024, 0, stream>>>(target, ws, out, N, D, 1 + 4 * D + N);
}